// Round 9
// baseline (351.656 us; speedup 1.0000x reference)
//
#include <hip/hip_runtime.h>
#include <hip/hip_bf16.h>

#define NB 512
#define CIN 32
#define LEN 512
#define NE 8
#define NPOOL 16
#define DIN 16384
#define DOUT 768
#define HD 1024
#define F1 128

#define MT 192      // GEMM M tile (cn<=192 w.h.p. -> one pass, B read exactly once)
#define NT 64       // GEMM N tile (12 n-tiles over DOUT=768)
#define BK 32       // K step
#define NBUF 4      // B LDS pipeline depth (deterministically race-free)

typedef __attribute__((ext_vector_type(4))) float f32x4;
typedef __attribute__((ext_vector_type(8))) short s16x8;
typedef __attribute__((ext_vector_type(4))) unsigned int u32x4;

__device__ __forceinline__ float gelu_erf(float v) {
    return 0.5f * v * (1.0f + erff(v * 0.70710678118654752f));
}

__device__ __forceinline__ unsigned cvt_pk(float lo, float hi) {
    unsigned r;
    asm volatile("v_cvt_pk_bf16_f32 %0, %1, %2" : "=v"(r) : "v"(lo), "v"(hi));
    return r;
}

__device__ __forceinline__ unsigned short f2bf_u(float f) {
    union { float f; unsigned u; } x; x.f = f;
    unsigned r = x.u + 0x7fffu + ((x.u >> 16) & 1u);
    return (unsigned short)(r >> 16);
}

// async global->LDS DMA, 16B/lane, LDS dest = wave-uniform base + lane*16
__device__ __forceinline__ void gload_lds16(const void* gptr, void* lptr) {
    __builtin_amdgcn_global_load_lds(
        (const __attribute__((address_space(1))) unsigned int*)gptr,
        (__attribute__((address_space(3))) unsigned int*)lptr,
        16, 0, 0);
}

// ---------------- Kernel A: conv1d(k=3,pad=1) + GELU + avgpool(32) + BN ----------------
__global__ __launch_bounds__(256) void krouter_conv(
    const float* __restrict__ x, const float* __restrict__ cw, const float* __restrict__ cb,
    const float* __restrict__ bng, const float* __restrict__ bnb,
    const float* __restrict__ bnm, const float* __restrict__ bnv,
    float* __restrict__ h, int* __restrict__ cnt)
{
    __shared__ float xs[CIN * 264];
    int half = blockIdx.x;
    int b = blockIdx.y;
    int t = threadIdx.x;
    if (b == 0 && half == 0 && t < NE) cnt[t] = 0;

    int Lchunk0 = half * 64 - 1;
    const float* xb_ = x + (size_t)b * DIN;
    for (int idx = t; idx < CIN * 66; idx += 256) {
        int ci = idx / 66;
        int cc = idx - ci * 66;
        int gc = min(max(Lchunk0 + cc, 0), 127);
        f32x4 v = *(const f32x4*)(xb_ + ci * 512 + gc * 4);
        int byte = ci * 1056 + ((cc << 4) ^ (((cc >> 3) & 7) << 4));
        *(f32x4*)((char*)xs + byte) = v;
    }
    __syncthreads();

    int p  = t & 7;
    int pg = half * 8 + p;
    int cq = t >> 3;
    int co0 = cq * 2, co1 = co0 + 1;

    float sa[32], sb[32];
    #pragma unroll
    for (int i = 0; i < 32; ++i) { sa[i] = 0.f; sb[i] = 0.f; }

    for (int ci = 0; ci < CIN; ++ci) {
        float f[40];
        #pragma unroll
        for (int u = 0; u < 10; ++u) {
            int lc = p * 8 + u;
            int byte = ci * 1056 + ((lc << 4) ^ (((lc >> 3) & 7) << 4));
            f32x4 v = *(const f32x4*)((const char*)xs + byte);
            f[4*u+0] = v[0]; f[4*u+1] = v[1]; f[4*u+2] = v[2]; f[4*u+3] = v[3];
        }
        if (pg == 0)  f[3]  = 0.f;
        if (pg == 15) f[36] = 0.f;
        float wa0 = cw[co0*96 + ci*3 + 0], wa1 = cw[co0*96 + ci*3 + 1], wa2 = cw[co0*96 + ci*3 + 2];
        float wb0 = cw[co1*96 + ci*3 + 0], wb1 = cw[co1*96 + ci*3 + 1], wb2 = cw[co1*96 + ci*3 + 2];
        #pragma unroll
        for (int i = 0; i < 32; ++i) {
            sa[i] = fmaf(f[i+3], wa0, fmaf(f[i+4], wa1, fmaf(f[i+5], wa2, sa[i])));
            sb[i] = fmaf(f[i+3], wb0, fmaf(f[i+4], wb1, fmaf(f[i+5], wb2, sb[i])));
        }
    }

    float ba = cb[co0], bbv = cb[co1];
    float ma = 0.f, mb = 0.f;
    #pragma unroll
    for (int i = 0; i < 32; ++i) { ma += gelu_erf(sa[i] + ba); mb += gelu_erf(sb[i] + bbv); }
    ma *= (1.f / 32.f); mb *= (1.f / 32.f);

    int oa = co0 * NPOOL + pg, ob = co1 * NPOOL + pg;
    float ra = (ma - bnm[oa]) * rsqrtf(bnv[oa] + 1e-5f) * bng[oa] + bnb[oa];
    float rb = (mb - bnm[ob]) * rsqrtf(bnv[ob] + 1e-5f) * bng[ob] + bnb[ob];
    h[(size_t)b * HD + oa] = ra;
    h[(size_t)b * HD + ob] = rb;
}

// ---------------- Kernel B: fc1+GELU, fc2, gumbel softmax, top-2, expert row lists ----------
__global__ __launch_bounds__(256) void krouter_fc(
    const float* __restrict__ h, const float* __restrict__ f1w, const float* __restrict__ f1b,
    const float* __restrict__ f2w, const float* __restrict__ f2b,
    const float* __restrict__ gu,
    int* __restrict__ top2e, float* __restrict__ top2w,
    int* __restrict__ cnt, int* __restrict__ rowlist, float* __restrict__ roww)
{
    __shared__ float hs[8 * HD];
    __shared__ float h1s[8 * F1];
    __shared__ float lg[8 * NE];

    int bb = blockIdx.x * 8;
    int t = threadIdx.x;

    const f32x4* hg = (const f32x4*)(h + (size_t)bb * HD);
    f32x4* hs4 = (f32x4*)hs;
    #pragma unroll
    for (int u = 0; u < 8; ++u) hs4[t + 256 * u] = hg[t + 256 * u];
    __syncthreads();

    int j = t & 127;
    int pr = t >> 7;
    float acc[4] = {0.f, 0.f, 0.f, 0.f};
    const f32x4* w4 = (const f32x4*)(f1w + (size_t)j * HD);
    for (int k4 = 0; k4 < 256; ++k4) {
        f32x4 w = w4[k4];
        #pragma unroll
        for (int g = 0; g < 4; ++g) {
            f32x4 hv = hs4[(pr * 4 + g) * 256 + k4];
            acc[g] += w[0]*hv[0] + w[1]*hv[1] + w[2]*hv[2] + w[3]*hv[3];
        }
    }
    float bj = f1b[j];
    #pragma unroll
    for (int g = 0; g < 4; ++g) h1s[(pr * 4 + g) * F1 + j] = gelu_erf(acc[g] + bj);
    __syncthreads();

    if (t < 64) {
        int bi = t >> 3, e = t & 7;
        float s = f2b[e];
        const float* w = f2w + e * F1;
        const float* hh = h1s + bi * F1;
        #pragma unroll 8
        for (int k = 0; k < F1; ++k) s += hh[k] * w[k];
        lg[bi * NE + e] = s;
    }
    __syncthreads();

    if (t < 8) {
        int bi = t; int b = bb + bi;
        float r[NE];
        float mx = -1e30f;
        #pragma unroll
        for (int e = 0; e < NE; ++e) {
            float g = -logf(-logf(gu[b * NE + e]));
            r[e] = lg[bi * NE + e] + g;
            mx = fmaxf(mx, r[e]);
        }
        float sum = 0.f;
        #pragma unroll
        for (int e = 0; e < NE; ++e) { r[e] = expf(r[e] - mx); sum += r[e]; }
        float inv = 1.f / sum;
        #pragma unroll
        for (int e = 0; e < NE; ++e) r[e] *= inv;
        int e0 = 0; float v0 = r[0];
        #pragma unroll
        for (int e = 1; e < NE; ++e) if (r[e] > v0) { v0 = r[e]; e0 = e; }
        int e1 = -1; float v1 = -1.f;
        #pragma unroll
        for (int e = 0; e < NE; ++e) { if (e == e0) continue; if (r[e] > v1) { v1 = r[e]; e1 = e; } }
        float den = v0 + v1 + 1e-8f;
        float w0 = v0 / den, w1 = v1 / den;
        top2e[b * 2 + 0] = e0; top2e[b * 2 + 1] = e1;
        top2w[b * 2 + 0] = w0; top2w[b * 2 + 1] = w1;
        int p0 = atomicAdd(&cnt[e0], 1);
        rowlist[e0 * NB + p0] = b * 2 + 0; roww[e0 * NB + p0] = w0;
        int p1 = atomicAdd(&cnt[e1], 1);
        rowlist[e1 * NB + p1] = b * 2 + 1; roww[e1 * NB + p1] = w1;
    }
}

// ---------------- Kernel C: gathered expert GEMM, counted-vmcnt deep pipeline -------------
// MT=192, NT=64, BK=32, 512 thr (8 waves 4m x 2n, wave tile 48x32).
// A: per-lane fragment loads fp32 x -> regs -> cvt_pk (NO A LDS, no vmcnt coupling).
// B: global_load_lds DMA, 4 LDS buffers, issued 2 steps ahead; per-step wait is
//    s_waitcnt vmcnt(8) (B(s+1), A(s+1)x6, B(s+2) stay in flight) + raw s_barrier.
__global__ __launch_bounds__(512, 4) void kgemm(
    const float* __restrict__ x, const float* __restrict__ ew,
    const int* __restrict__ cnt, const int* __restrict__ rowlist, const float* __restrict__ roww,
    unsigned short* __restrict__ ypart, int nkc, int kch)
{
    // bijective XCD-chunk swizzle: contiguous wg range per XCD = one expert
    int nwg = gridDim.x;
    int cpx = nwg >> 3;
    int wg = (blockIdx.x & 7) * cpx + (blockIdx.x >> 3);
    int nt = wg % 12;
    int kc = (wg / 12) % nkc;
    int e  = wg / (12 * nkc);
    int cn = cnt[e];

    __shared__ __align__(16) char Bs[NBUF][BK * NT * 4];   // 4 x 8KB fp32 [k][n-chunk swz]

    int t = threadIdx.x;
    int wid = t >> 6, lane = t & 63;
    int wm = wid >> 1, wn = wid & 1;
    int g = lane >> 4;
    int NS = kch / BK;
    int k0 = kc * kch;

    // --- B DMA: wave wid stages seg wid (1KB = 4 k-rows x 16 chunks), src pre-swizzled ---
    const char* gB = (const char*)ew + (size_t)e * DIN * DOUT * 4
                   + (size_t)k0 * (DOUT * 4) + nt * NT * 4;
    int bk_ = wid * 4 + (lane >> 4);
    int bc_ = lane & 15;
    int bkey = ((bk_ >> 3) & 3) << 2;
    const char* gp = gB + (size_t)bk_ * (DOUT * 4) + ((bc_ ^ bkey) << 4);
    int ldsB = wid * 1024;

    const float* xk = x + k0 + g * 8;   // per-lane A base (row added per frag)

    for (int row0 = 0; row0 < cn; row0 += MT) {
        int mloc = min(MT, cn - row0);
        bool wact = (wm * 48 < mloc);

        // per-lane A row gather bases (3 m-frags of 16 rows each)
        size_t abase[3];
        #pragma unroll
        for (int mi = 0; mi < 3; ++mi) {
            int m = wm * 48 + mi * 16 + (lane & 15);
            int mc = min(m, mloc - 1);
            abase[mi] = (size_t)(rowlist[e * NB + row0 + mc] >> 1) * DIN;
        }

        f32x4 acc[3][2];
        #pragma unroll
        for (int i = 0; i < 3; ++i)
            #pragma unroll
            for (int jj = 0; jj < 2; ++jj) acc[i][jj] = (f32x4){0.f, 0.f, 0.f, 0.f};

        f32x4 An[3][2];                 // next-step A (fp32)
        const char* bp = gp;

        auto loadA = [&](int s) {
            #pragma unroll
            for (int mi = 0; mi < 3; ++mi) {
                const f32x4* p = (const f32x4*)(xk + abase[mi] + s * BK);
                An[mi][0] = p[0]; An[mi][1] = p[1];
            }
        };
        auto stageB = [&](int s) {
            gload_lds16(bp + (size_t)s * (BK * DOUT * 4), (char*)Bs[s & (NBUF - 1)] + ldsB);
        };

        // prologue: queue = [B(0), A(0)x6, B(1)]  (oldest first)
        stageB(0);
        loadA(0);
        if (1 < NS) stageB(1);

        for (int s = 0; s < NS; ++s) {
            // convert A(s) -> bf16 frags (compiler auto-waits A(s): vmcnt leaves B(s+1) alive)
            s16x8 af[3];
            #pragma unroll
            for (int mi = 0; mi < 3; ++mi) {
                union { u32x4 u; s16x8 v; } c;
                c.u[0] = cvt_pk(An[mi][0][0], An[mi][0][1]);
                c.u[1] = cvt_pk(An[mi][0][2], An[mi][0][3]);
                c.u[2] = cvt_pk(An[mi][1][0], An[mi][1][1]);
                c.u[3] = cvt_pk(An[mi][1][2], An[mi][1][3]);
                af[mi] = c.v;
            }
            // issue next-step work: A(s+1) first (newer than B(s+1)!), then B(s+2)
            if (s + 1 < NS) loadA(s + 1);
            if (s + 2 < NS) stageB(s + 2);
            __builtin_amdgcn_sched_barrier(0);
            // wait B(s) landed, keep B(s+1)/A(s+1)/B(s+2) in flight
            if (s + 2 < NS)      asm volatile("s_waitcnt vmcnt(8)" ::: "memory");
            else if (s + 1 < NS) asm volatile("s_waitcnt vmcnt(7)" ::: "memory");
            else                 asm volatile("s_waitcnt vmcnt(0)" ::: "memory");
            __builtin_amdgcn_sched_barrier(0);
            __builtin_amdgcn_s_barrier();
            __builtin_amdgcn_sched_barrier(0);

            if (wact) {
                const char* Bb = Bs[s & (NBUF - 1)];
                __builtin_amdgcn_s_setprio(1);
                #pragma unroll
                for (int ni = 0; ni < 2; ++ni) {
                    int n = wn * 32 + ni * 16 + (lane & 15);
                    int cb = (((n >> 2) ^ (g << 2)) << 4) + ((n & 3) << 2);
                    float v[8];
                    #pragma unroll
                    for (int j = 0; j < 8; ++j)
                        v[j] = *(const float*)(Bb + (g * 8 + j) * 256 + cb);
                    union { u32x4 u; s16x8 v8; } bf;
                    bf.u[0] = cvt_pk(v[0], v[1]); bf.u[1] = cvt_pk(v[2], v[3]);
                    bf.u[2] = cvt_pk(v[4], v[5]); bf.u[3] = cvt_pk(v[6], v[7]);
                    #pragma unroll
                    for (int mi = 0; mi < 3; ++mi)
                        acc[mi][ni] = __builtin_amdgcn_mfma_f32_16x16x32_bf16(af[mi], bf.v8, acc[mi][ni], 0, 0, 0);
                }
                __builtin_amdgcn_s_setprio(0);
            }
            // NO end-of-step barrier: buffer (s+2)%4 != any buffer readable this step,
            // and reuse distance 4 sits behind two s_barriers (deterministically safe).
        }

        // ---- epilogue: gate weight, bf16 scatter to per-(slot,kc) partial plane ----
        if (wact) {
            #pragma unroll
            for (int mi = 0; mi < 3; ++mi) {
                #pragma unroll
                for (int rg = 0; rg < 4; ++rg) {
                    int m = wm * 48 + mi * 16 + g * 4 + rg;
                    if (m < mloc) {
                        int ent = rowlist[e * NB + row0 + m];
                        float wgt = roww[e * NB + row0 + m];
                        int ob = ent >> 1, slot = ent & 1;
                        unsigned short* dst = ypart + ((size_t)(slot * nkc + kc) * NB + ob) * DOUT
                                            + nt * NT + wn * 32 + (lane & 15);
                        #pragma unroll
                        for (int ni = 0; ni < 2; ++ni)
                            dst[ni * 16] = f2bf_u(acc[mi][ni][rg] * wgt);
                    }
                }
            }
        }
        __syncthreads();   // full drain between (rare) multi-pass iterations
    }
}

// ---------------- Kernel D: combine bf16 partial planes + weighted expert bias ------------
__global__ __launch_bounds__(256) void kcombine(
    const unsigned short* __restrict__ ypart,
    const int* __restrict__ top2e, const float* __restrict__ top2w,
    const float* __restrict__ eb, float* __restrict__ out, int nplanes)
{
    int b = blockIdx.y;
    int n = blockIdx.x * 256 + threadIdx.x;
    float s = 0.f;
    for (int p = 0; p < nplanes; ++p) {
        unsigned v = ypart[((size_t)p * NB + b) * DOUT + n];
        union { unsigned u; float f; } c; c.u = v << 16;
        s += c.f;
    }
    int e0 = top2e[b * 2], e1 = top2e[b * 2 + 1];
    float w0 = top2w[b * 2], w1 = top2w[b * 2 + 1];
    s += w0 * eb[e0 * DOUT + n] + w1 * eb[e1 * DOUT + n];
    out[(size_t)b * DOUT + n] = s;
}

extern "C" void kernel_launch(void* const* d_in, const int* in_sizes, int n_in,
                              void* d_out, int out_size, void* d_ws, size_t ws_size,
                              hipStream_t stream)
{
    const float* x   = (const float*)d_in[0];
    const float* gu  = (const float*)d_in[1];
    const float* cw  = (const float*)d_in[2];
    const float* cb  = (const float*)d_in[3];
    const float* bng = (const float*)d_in[4];
    const float* bnb = (const float*)d_in[5];
    const float* bnm = (const float*)d_in[6];
    const float* bnv = (const float*)d_in[7];
    const float* f1w = (const float*)d_in[8];
    const float* f1b = (const float*)d_in[9];
    const float* f2w = (const float*)d_in[10];
    const float* f2b = (const float*)d_in[11];
    const float* ew  = (const float*)d_in[12];
    const float* eb  = (const float*)d_in[13];

    int nkc = (ws_size >= (size_t)40 * 1024 * 1024) ? 16 : 8;
    int kch = DIN / nkc;

    char* ws = (char*)d_ws;
    size_t off = 0;
    float* h       = (float*)(ws + off); off += (size_t)NB * HD * 4;
    int*   top2e   = (int*)(ws + off);   off += (size_t)NB * 2 * 4;
    float* top2w   = (float*)(ws + off); off += (size_t)NB * 2 * 4;
    int*   cnt     = (int*)(ws + off);   off += 256;
    int*   rowlist = (int*)(ws + off);   off += (size_t)NE * NB * 4;
    float* roww    = (float*)(ws + off); off += (size_t)NE * NB * 4;
    unsigned short* ypart = (unsigned short*)(ws + off);
    off += (size_t)2 * nkc * NB * DOUT * 2;

    krouter_conv<<<dim3(2, NB), 256, 0, stream>>>(x, cw, cb, bng, bnb, bnm, bnv, h, cnt);
    krouter_fc<<<NB / 8, 256, 0, stream>>>(h, f1w, f1b, f2w, f2b, gu,
                                           top2e, top2w, cnt, rowlist, roww);
    kgemm<<<NE * nkc * 12, 512, 0, stream>>>(x, ew, cnt, rowlist, roww, ypart, nkc, kch);
    kcombine<<<dim3(3, NB), 256, 0, stream>>>(ypart, top2e, top2w, eb, (float*)d_out, 2 * nkc);
}

// Round 10
// 259.771 us; speedup vs baseline: 1.3537x; 1.3537x over previous
//
#include <hip/hip_runtime.h>
#include <hip/hip_bf16.h>

#define NB 512
#define CIN 32
#define LEN 512
#define NE 8
#define NPOOL 16
#define DIN 16384
#define DOUT 768
#define HD 1024
#define F1 128

#define MT 256      // GEMM M tile (one pass covers any realistic cn)
#define NT 64       // GEMM N tile (12 n-tiles over DOUT=768)
#define BK 32       // K step
#define NBUF 4      // B LDS pipeline depth

typedef __attribute__((ext_vector_type(4))) float f32x4;
typedef __attribute__((ext_vector_type(8))) short s16x8;
typedef __attribute__((ext_vector_type(4))) unsigned int u32x4;

__device__ __forceinline__ float gelu_erf(float v) {
    return 0.5f * v * (1.0f + erff(v * 0.70710678118654752f));
}

__device__ __forceinline__ unsigned cvt_pk(float lo, float hi) {
    unsigned r;
    asm volatile("v_cvt_pk_bf16_f32 %0, %1, %2" : "=v"(r) : "v"(lo), "v"(hi));
    return r;
}

__device__ __forceinline__ unsigned short f2bf_u(float f) {
    union { float f; unsigned u; } x; x.f = f;
    unsigned r = x.u + 0x7fffu + ((x.u >> 16) & 1u);
    return (unsigned short)(r >> 16);
}

// async global->LDS DMA, 16B/lane, LDS dest = wave-uniform base + lane*16
__device__ __forceinline__ void gload_lds16(const void* gptr, void* lptr) {
    __builtin_amdgcn_global_load_lds(
        (const __attribute__((address_space(1))) unsigned int*)gptr,
        (__attribute__((address_space(3))) unsigned int*)lptr,
        16, 0, 0);
}

// ---------------- Kernel A: conv1d(k=3,pad=1) + GELU + avgpool(32) + BN ----------------
__global__ __launch_bounds__(256) void krouter_conv(
    const float* __restrict__ x, const float* __restrict__ cw, const float* __restrict__ cb,
    const float* __restrict__ bng, const float* __restrict__ bnb,
    const float* __restrict__ bnm, const float* __restrict__ bnv,
    float* __restrict__ h, int* __restrict__ cnt)
{
    __shared__ float xs[CIN * 264];
    int half = blockIdx.x;
    int b = blockIdx.y;
    int t = threadIdx.x;
    if (b == 0 && half == 0 && t < NE) cnt[t] = 0;

    int Lchunk0 = half * 64 - 1;
    const float* xb_ = x + (size_t)b * DIN;
    for (int idx = t; idx < CIN * 66; idx += 256) {
        int ci = idx / 66;
        int cc = idx - ci * 66;
        int gc = min(max(Lchunk0 + cc, 0), 127);
        f32x4 v = *(const f32x4*)(xb_ + ci * 512 + gc * 4);
        int byte = ci * 1056 + ((cc << 4) ^ (((cc >> 3) & 7) << 4));
        *(f32x4*)((char*)xs + byte) = v;
    }
    __syncthreads();

    int p  = t & 7;
    int pg = half * 8 + p;
    int cq = t >> 3;
    int co0 = cq * 2, co1 = co0 + 1;

    float sa[32], sb[32];
    #pragma unroll
    for (int i = 0; i < 32; ++i) { sa[i] = 0.f; sb[i] = 0.f; }

    for (int ci = 0; ci < CIN; ++ci) {
        float f[40];
        #pragma unroll
        for (int u = 0; u < 10; ++u) {
            int lc = p * 8 + u;
            int byte = ci * 1056 + ((lc << 4) ^ (((lc >> 3) & 7) << 4));
            f32x4 v = *(const f32x4*)((const char*)xs + byte);
            f[4*u+0] = v[0]; f[4*u+1] = v[1]; f[4*u+2] = v[2]; f[4*u+3] = v[3];
        }
        if (pg == 0)  f[3]  = 0.f;
        if (pg == 15) f[36] = 0.f;
        float wa0 = cw[co0*96 + ci*3 + 0], wa1 = cw[co0*96 + ci*3 + 1], wa2 = cw[co0*96 + ci*3 + 2];
        float wb0 = cw[co1*96 + ci*3 + 0], wb1 = cw[co1*96 + ci*3 + 1], wb2 = cw[co1*96 + ci*3 + 2];
        #pragma unroll
        for (int i = 0; i < 32; ++i) {
            sa[i] = fmaf(f[i+3], wa0, fmaf(f[i+4], wa1, fmaf(f[i+5], wa2, sa[i])));
            sb[i] = fmaf(f[i+3], wb0, fmaf(f[i+4], wb1, fmaf(f[i+5], wb2, sb[i])));
        }
    }

    float ba = cb[co0], bbv = cb[co1];
    float ma = 0.f, mb = 0.f;
    #pragma unroll
    for (int i = 0; i < 32; ++i) { ma += gelu_erf(sa[i] + ba); mb += gelu_erf(sb[i] + bbv); }
    ma *= (1.f / 32.f); mb *= (1.f / 32.f);

    int oa = co0 * NPOOL + pg, ob = co1 * NPOOL + pg;
    float ra = (ma - bnm[oa]) * rsqrtf(bnv[oa] + 1e-5f) * bng[oa] + bnb[oa];
    float rb = (mb - bnm[ob]) * rsqrtf(bnv[ob] + 1e-5f) * bng[ob] + bnb[ob];
    h[(size_t)b * HD + oa] = ra;
    h[(size_t)b * HD + ob] = rb;
}

// ---------------- Kernel B: fc1+GELU, fc2, gumbel softmax, top-2, expert row lists ----------
__global__ __launch_bounds__(256) void krouter_fc(
    const float* __restrict__ h, const float* __restrict__ f1w, const float* __restrict__ f1b,
    const float* __restrict__ f2w, const float* __restrict__ f2b,
    const float* __restrict__ gu,
    int* __restrict__ top2e, float* __restrict__ top2w,
    int* __restrict__ cnt, int* __restrict__ rowlist, float* __restrict__ roww)
{
    __shared__ float hs[8 * HD];
    __shared__ float h1s[8 * F1];
    __shared__ float lg[8 * NE];

    int bb = blockIdx.x * 8;
    int t = threadIdx.x;

    const f32x4* hg = (const f32x4*)(h + (size_t)bb * HD);
    f32x4* hs4 = (f32x4*)hs;
    #pragma unroll
    for (int u = 0; u < 8; ++u) hs4[t + 256 * u] = hg[t + 256 * u];
    __syncthreads();

    int j = t & 127;
    int pr = t >> 7;
    float acc[4] = {0.f, 0.f, 0.f, 0.f};
    const f32x4* w4 = (const f32x4*)(f1w + (size_t)j * HD);
    for (int k4 = 0; k4 < 256; ++k4) {
        f32x4 w = w4[k4];
        #pragma unroll
        for (int g = 0; g < 4; ++g) {
            f32x4 hv = hs4[(pr * 4 + g) * 256 + k4];
            acc[g] += w[0]*hv[0] + w[1]*hv[1] + w[2]*hv[2] + w[3]*hv[3];
        }
    }
    float bj = f1b[j];
    #pragma unroll
    for (int g = 0; g < 4; ++g) h1s[(pr * 4 + g) * F1 + j] = gelu_erf(acc[g] + bj);
    __syncthreads();

    if (t < 64) {
        int bi = t >> 3, e = t & 7;
        float s = f2b[e];
        const float* w = f2w + e * F1;
        const float* hh = h1s + bi * F1;
        #pragma unroll 8
        for (int k = 0; k < F1; ++k) s += hh[k] * w[k];
        lg[bi * NE + e] = s;
    }
    __syncthreads();

    if (t < 8) {
        int bi = t; int b = bb + bi;
        float r[NE];
        float mx = -1e30f;
        #pragma unroll
        for (int e = 0; e < NE; ++e) {
            float g = -logf(-logf(gu[b * NE + e]));
            r[e] = lg[bi * NE + e] + g;
            mx = fmaxf(mx, r[e]);
        }
        float sum = 0.f;
        #pragma unroll
        for (int e = 0; e < NE; ++e) { r[e] = expf(r[e] - mx); sum += r[e]; }
        float inv = 1.f / sum;
        #pragma unroll
        for (int e = 0; e < NE; ++e) r[e] *= inv;
        int e0 = 0; float v0 = r[0];
        #pragma unroll
        for (int e = 1; e < NE; ++e) if (r[e] > v0) { v0 = r[e]; e0 = e; }
        int e1 = -1; float v1 = -1.f;
        #pragma unroll
        for (int e = 0; e < NE; ++e) { if (e == e0) continue; if (r[e] > v1) { v1 = r[e]; e1 = e; } }
        float den = v0 + v1 + 1e-8f;
        float w0 = v0 / den, w1 = v1 / den;
        top2e[b * 2 + 0] = e0; top2e[b * 2 + 1] = e1;
        top2w[b * 2 + 0] = w0; top2w[b * 2 + 1] = w1;
        int p0 = atomicAdd(&cnt[e0], 1);
        rowlist[e0 * NB + p0] = b * 2 + 0; roww[e0 * NB + p0] = w0;
        int p1 = atomicAdd(&cnt[e1], 1);
        rowlist[e1 * NB + p1] = b * 2 + 1; roww[e1 * NB + p1] = w1;
    }
}

// ---------------- Kernel C: gathered expert GEMM, A-LDS + counted-vmcnt B pipeline --------
// MT=256, NT=64, BK=32, 512 thr (8 waves 4m x 2n, wave tile 64x32). LDS 64KB -> 2 blk/CU.
// B: global_load_lds DMA, 4 buffers, issued 2 steps ahead; steady wait = vmcnt(6)
//    (keeps B(s+1), A(s+1)x4, B(s+2) in flight; drains exactly B(s)).
// A: all 512 threads load 16 fp32 (coalesced), cvt_pk -> 2x ds_write_b128 into quad-XOR
//    swizzled [256][64B] bf16 tile, written AFTER the MFMA cluster (its A-reg wait is
//    vmcnt(1): B(s+2) survives). Shared by all waves: A L2 traffic 12x-bf16, not 24x-fp32.
__global__ __launch_bounds__(512, 4) void kgemm(
    const float* __restrict__ x, const float* __restrict__ ew,
    const int* __restrict__ cnt, const int* __restrict__ rowlist, const float* __restrict__ roww,
    unsigned short* __restrict__ ypart, int nkc, int kch)
{
    // bijective XCD-chunk swizzle: contiguous 192-wg range per XCD = one expert
    int nwg = gridDim.x;
    int cpx = nwg >> 3;
    int wg = (blockIdx.x & 7) * cpx + (blockIdx.x >> 3);
    int nt = wg % 12;
    int kc = (wg / 12) % nkc;
    int e  = wg / (12 * nkc);
    int cn = cnt[e];
    if (cn <= 0) return;

    __shared__ __align__(16) char As[2][MT * 64];         // 2 x 16KB bf16 [m][quad swz]
    __shared__ __align__(16) char Bs[NBUF][BK * NT * 4];  // 4 x 8KB fp32 [k][n-chunk swz]

    int t = threadIdx.x;
    int wid = t >> 6, lane = t & 63;
    int wm = wid >> 1, wn = wid & 1;
    int g = lane >> 4;
    int NS = kch / BK;
    int k0 = kc * kch;

    // --- B DMA: wave wid stages seg wid (1KB = 4 k-rows x 16 chunks), src pre-swizzled ---
    const char* gB = (const char*)ew + (size_t)e * DIN * DOUT * 4
                   + (size_t)k0 * (DOUT * 4) + nt * NT * 4;
    int bk_ = wid * 4 + (lane >> 4);
    int bc_ = lane & 15;
    int bkey = ((bk_ >> 3) & 3) << 2;
    const char* gp = gB + (size_t)bk_ * (DOUT * 4) + ((bc_ ^ bkey) << 4);
    int ldsB = wid * 1024;

    // --- A staging: thread t -> row t>>1 (0..255), half h=t&1 (16 fp32 = quads 2h,2h+1) ---
    int arow = t >> 1, ah = t & 1;
    int akey = (arow ^ (arow >> 2)) & 3;
    int aw0 = arow * 64 + (((2 * ah) ^ akey) << 4);
    int aw1 = arow * 64 + (((2 * ah + 1) ^ akey) << 4);

    for (int row0 = 0; row0 < cn; row0 += MT) {
        int mloc = min(MT, cn - row0);
        bool wact = (wm * 64 < mloc);

        int arc = min(arow, mloc - 1);
        const float* axp = x + (size_t)(rowlist[e * NB + row0 + arc] >> 1) * DIN
                         + k0 + ah * 16;

        f32x4 acc[4][2];
        #pragma unroll
        for (int i = 0; i < 4; ++i)
            #pragma unroll
            for (int jj = 0; jj < 2; ++jj) acc[i][jj] = (f32x4){0.f, 0.f, 0.f, 0.f};

        f32x4 An[4];
        const char* bp = gp;

        auto loadA = [&](int s) {
            const f32x4* p = (const f32x4*)(axp + (size_t)s * BK);
            An[0] = p[0]; An[1] = p[1]; An[2] = p[2]; An[3] = p[3];
        };
        auto stageB = [&](int s) {
            gload_lds16(bp + (size_t)s * ((size_t)BK * DOUT * 4),
                        (char*)Bs[s & (NBUF - 1)] + ldsB);
        };
        auto writeA = [&](int bi) {
            u32x4 q0, q1;
            q0[0] = cvt_pk(An[0][0], An[0][1]); q0[1] = cvt_pk(An[0][2], An[0][3]);
            q0[2] = cvt_pk(An[1][0], An[1][1]); q0[3] = cvt_pk(An[1][2], An[1][3]);
            q1[0] = cvt_pk(An[2][0], An[2][1]); q1[1] = cvt_pk(An[2][2], An[2][3]);
            q1[2] = cvt_pk(An[3][0], An[3][1]); q1[3] = cvt_pk(An[3][2], An[3][3]);
            *(u32x4*)(As[bi] + aw0) = q0;
            *(u32x4*)(As[bi] + aw1) = q1;
        };

        // prologue: A(0) oldest is fine (its wait keeps B(0),B(1) in flight)
        loadA(0);
        stageB(0);
        if (NS > 1) stageB(1);
        writeA(0);                    // auto-wait vmcnt(2): A(0) done, B(0)/B(1) fly

        for (int s = 0; s < NS; ++s) {
            if (s + 1 < NS) loadA(s + 1);
            if (s + 2 < NS) stageB(s + 2);
            __builtin_amdgcn_sched_barrier(0);
            // steady queue: [B(s), B(s+1), A(s+1)x4, B(s+2)] -> drain exactly B(s);
            // lgkmcnt(0) publishes last step's A ds_writes before the barrier.
            if (s + 2 < NS)      asm volatile("s_waitcnt vmcnt(6) lgkmcnt(0)" ::: "memory");
            else if (s + 1 < NS) asm volatile("s_waitcnt vmcnt(5) lgkmcnt(0)" ::: "memory");
            else                 asm volatile("s_waitcnt vmcnt(0) lgkmcnt(0)" ::: "memory");
            __builtin_amdgcn_sched_barrier(0);
            __builtin_amdgcn_s_barrier();
            __builtin_amdgcn_sched_barrier(0);

            if (wact) {
                const char* Ab = As[s & 1];
                const char* Bb = Bs[s & (NBUF - 1)];
                __builtin_amdgcn_s_setprio(1);
                s16x8 af[4];
                #pragma unroll
                for (int mi = 0; mi < 4; ++mi) {
                    int m = wm * 64 + mi * 16 + (lane & 15);
                    int key = (m ^ (m >> 2)) & 3;
                    af[mi] = *(const s16x8*)(Ab + m * 64 + ((g ^ key) << 4));
                }
                #pragma unroll
                for (int ni = 0; ni < 2; ++ni) {
                    int n = wn * 32 + ni * 16 + (lane & 15);
                    int cb = (((n >> 2) ^ (g << 2)) << 4) + ((n & 3) << 2);
                    float v[8];
                    #pragma unroll
                    for (int j = 0; j < 8; ++j)
                        v[j] = *(const float*)(Bb + (g * 8 + j) * 256 + cb);
                    union { u32x4 u; s16x8 v8; } bf;
                    bf.u[0] = cvt_pk(v[0], v[1]); bf.u[1] = cvt_pk(v[2], v[3]);
                    bf.u[2] = cvt_pk(v[4], v[5]); bf.u[3] = cvt_pk(v[6], v[7]);
                    #pragma unroll
                    for (int mi = 0; mi < 4; ++mi)
                        acc[mi][ni] = __builtin_amdgcn_mfma_f32_16x16x32_bf16(af[mi], bf.v8, acc[mi][ni], 0, 0, 0);
                }
                __builtin_amdgcn_s_setprio(0);
            }
            __builtin_amdgcn_sched_barrier(0);
            if (s + 1 < NS) writeA((s + 1) & 1);   // A-reg wait: vmcnt(1), B(s+2) alive.
            // Target As[(s+1)&1] was last read by MFMA(s-1), behind this step's barrier.
        }

        // ---- epilogue: gate weight, bf16 scatter to per-(slot,kc) partial plane ----
        if (wact) {
            #pragma unroll
            for (int mi = 0; mi < 4; ++mi) {
                #pragma unroll
                for (int rg = 0; rg < 4; ++rg) {
                    int m = wm * 64 + mi * 16 + g * 4 + rg;
                    if (m < mloc) {
                        int ent = rowlist[e * NB + row0 + m];
                        float wgt = roww[e * NB + row0 + m];
                        int ob = ent >> 1, slot = ent & 1;
                        unsigned short* dst = ypart + ((size_t)(slot * nkc + kc) * NB + ob) * DOUT
                                            + nt * NT + wn * 32 + (lane & 15);
                        #pragma unroll
                        for (int ni = 0; ni < 2; ++ni)
                            dst[ni * 16] = f2bf_u(acc[mi][ni][rg] * wgt);
                    }
                }
            }
        }
        // full drain between (rare) multi-pass iterations
        asm volatile("s_waitcnt vmcnt(0) lgkmcnt(0)" ::: "memory");
        __builtin_amdgcn_s_barrier();
    }
}

// ---------------- Kernel D: combine bf16 partial planes + weighted expert bias ------------
__global__ __launch_bounds__(256) void kcombine(
    const unsigned short* __restrict__ ypart,
    const int* __restrict__ top2e, const float* __restrict__ top2w,
    const float* __restrict__ eb, float* __restrict__ out, int nplanes)
{
    int b = blockIdx.y;
    int n = blockIdx.x * 256 + threadIdx.x;
    float s = 0.f;
    for (int p = 0; p < nplanes; ++p) {
        unsigned v = ypart[((size_t)p * NB + b) * DOUT + n];
        union { unsigned u; float f; } c; c.u = v << 16;
        s += c.f;
    }
    int e0 = top2e[b * 2], e1 = top2e[b * 2 + 1];
    float w0 = top2w[b * 2], w1 = top2w[b * 2 + 1];
    s += w0 * eb[e0 * DOUT + n] + w1 * eb[e1 * DOUT + n];
    out[(size_t)b * DOUT + n] = s;
}

extern "C" void kernel_launch(void* const* d_in, const int* in_sizes, int n_in,
                              void* d_out, int out_size, void* d_ws, size_t ws_size,
                              hipStream_t stream)
{
    const float* x   = (const float*)d_in[0];
    const float* gu  = (const float*)d_in[1];
    const float* cw  = (const float*)d_in[2];
    const float* cb  = (const float*)d_in[3];
    const float* bng = (const float*)d_in[4];
    const float* bnb = (const float*)d_in[5];
    const float* bnm = (const float*)d_in[6];
    const float* bnv = (const float*)d_in[7];
    const float* f1w = (const float*)d_in[8];
    const float* f1b = (const float*)d_in[9];
    const float* f2w = (const float*)d_in[10];
    const float* f2b = (const float*)d_in[11];
    const float* ew  = (const float*)d_in[12];
    const float* eb  = (const float*)d_in[13];

    int nkc = (ws_size >= (size_t)40 * 1024 * 1024) ? 16 : 8;
    int kch = DIN / nkc;

    char* ws = (char*)d_ws;
    size_t off = 0;
    float* h       = (float*)(ws + off); off += (size_t)NB * HD * 4;
    int*   top2e   = (int*)(ws + off);   off += (size_t)NB * 2 * 4;
    float* top2w   = (float*)(ws + off); off += (size_t)NB * 2 * 4;
    int*   cnt     = (int*)(ws + off);   off += 256;
    int*   rowlist = (int*)(ws + off);   off += (size_t)NE * NB * 4;
    float* roww    = (float*)(ws + off); off += (size_t)NE * NB * 4;
    unsigned short* ypart = (unsigned short*)(ws + off);
    off += (size_t)2 * nkc * NB * DOUT * 2;

    krouter_conv<<<dim3(2, NB), 256, 0, stream>>>(x, cw, cb, bng, bnb, bnm, bnv, h, cnt);
    krouter_fc<<<NB / 8, 256, 0, stream>>>(h, f1w, f1b, f2w, f2b, gu,
                                           top2e, top2w, cnt, rowlist, roww);
    kgemm<<<NE * nkc * 12, 512, 0, stream>>>(x, ew, cnt, rowlist, roww, ypart, nkc, kch);
    kcombine<<<dim3(3, NB), 256, 0, stream>>>(ypart, top2e, top2w, eb, (float*)d_out, 2 * nkc);
}

// Round 11
// 253.357 us; speedup vs baseline: 1.3880x; 1.0253x over previous
//
#include <hip/hip_runtime.h>
#include <hip/hip_bf16.h>

#define NB 512
#define CIN 32
#define LEN 512
#define NE 8
#define NPOOL 16
#define DIN 16384
#define DOUT 768
#define HD 1024
#define F1 128

#define MT 256      // GEMM M tile (covers whole expert in one pass)
#define NT 128      // GEMM N tile (6 n-tiles over DOUT=768)
#define BK 32       // K step
#define NBUF 4      // pipeline depth for BOTH A and B LDS buffers

typedef __attribute__((ext_vector_type(4))) float f32x4;
typedef __attribute__((ext_vector_type(8))) short s16x8;
typedef __attribute__((ext_vector_type(4))) unsigned int u32x4;

__device__ __forceinline__ float gelu_erf(float v) {
    return 0.5f * v * (1.0f + erff(v * 0.70710678118654752f));
}

__device__ __forceinline__ unsigned cvt_pk(float lo, float hi) {
    unsigned r;
    asm volatile("v_cvt_pk_bf16_f32 %0, %1, %2" : "=v"(r) : "v"(lo), "v"(hi));
    return r;
}

__device__ __forceinline__ unsigned short f2bf_u(float f) {
    union { float f; unsigned u; } x; x.f = f;
    unsigned r = x.u + 0x7fffu + ((x.u >> 16) & 1u);
    return (unsigned short)(r >> 16);
}

// async global->LDS DMA, 16B/lane; global src is PER-LANE, LDS dest = base + lane*16
__device__ __forceinline__ void gload_lds16(const void* gptr, void* lptr) {
    __builtin_amdgcn_global_load_lds(
        (const __attribute__((address_space(1))) unsigned int*)gptr,
        (__attribute__((address_space(3))) unsigned int*)lptr,
        16, 0, 0);
}

// ---------------- Kernel 0: x fp32 -> bf16 (one-time; feeds kgemm A gather-DMA) ----------
__global__ __launch_bounds__(256) void kcvt(const float* __restrict__ x,
                                            unsigned short* __restrict__ xb)
{
    int i = blockIdx.x * 256 + threadIdx.x;
    const f32x4* src = (const f32x4*)(x + (size_t)i * 8);
    f32x4 v0 = src[0], v1 = src[1];
    u32x4 pk;
    pk[0] = cvt_pk(v0[0], v0[1]); pk[1] = cvt_pk(v0[2], v0[3]);
    pk[2] = cvt_pk(v1[0], v1[1]); pk[3] = cvt_pk(v1[2], v1[3]);
    *(u32x4*)(xb + (size_t)i * 8) = pk;
}

// ---------------- Kernel A: conv1d(k=3,pad=1) + GELU + avgpool(32) + BN ----------------
__global__ __launch_bounds__(256) void krouter_conv(
    const float* __restrict__ x, const float* __restrict__ cw, const float* __restrict__ cb,
    const float* __restrict__ bng, const float* __restrict__ bnb,
    const float* __restrict__ bnm, const float* __restrict__ bnv,
    float* __restrict__ h, int* __restrict__ cnt)
{
    __shared__ float xs[CIN * 264];
    int half = blockIdx.x;
    int b = blockIdx.y;
    int t = threadIdx.x;
    if (b == 0 && half == 0 && t < NE) cnt[t] = 0;

    int Lchunk0 = half * 64 - 1;
    const float* xb_ = x + (size_t)b * DIN;
    for (int idx = t; idx < CIN * 66; idx += 256) {
        int ci = idx / 66;
        int cc = idx - ci * 66;
        int gc = min(max(Lchunk0 + cc, 0), 127);
        f32x4 v = *(const f32x4*)(xb_ + ci * 512 + gc * 4);
        int byte = ci * 1056 + ((cc << 4) ^ (((cc >> 3) & 7) << 4));
        *(f32x4*)((char*)xs + byte) = v;
    }
    __syncthreads();

    int p  = t & 7;
    int pg = half * 8 + p;
    int cq = t >> 3;
    int co0 = cq * 2, co1 = co0 + 1;

    float sa[32], sb[32];
    #pragma unroll
    for (int i = 0; i < 32; ++i) { sa[i] = 0.f; sb[i] = 0.f; }

    for (int ci = 0; ci < CIN; ++ci) {
        float f[40];
        #pragma unroll
        for (int u = 0; u < 10; ++u) {
            int lc = p * 8 + u;
            int byte = ci * 1056 + ((lc << 4) ^ (((lc >> 3) & 7) << 4));
            f32x4 v = *(const f32x4*)((const char*)xs + byte);
            f[4*u+0] = v[0]; f[4*u+1] = v[1]; f[4*u+2] = v[2]; f[4*u+3] = v[3];
        }
        if (pg == 0)  f[3]  = 0.f;
        if (pg == 15) f[36] = 0.f;
        float wa0 = cw[co0*96 + ci*3 + 0], wa1 = cw[co0*96 + ci*3 + 1], wa2 = cw[co0*96 + ci*3 + 2];
        float wb0 = cw[co1*96 + ci*3 + 0], wb1 = cw[co1*96 + ci*3 + 1], wb2 = cw[co1*96 + ci*3 + 2];
        #pragma unroll
        for (int i = 0; i < 32; ++i) {
            sa[i] = fmaf(f[i+3], wa0, fmaf(f[i+4], wa1, fmaf(f[i+5], wa2, sa[i])));
            sb[i] = fmaf(f[i+3], wb0, fmaf(f[i+4], wb1, fmaf(f[i+5], wb2, sb[i])));
        }
    }

    float ba = cb[co0], bbv = cb[co1];
    float ma = 0.f, mb = 0.f;
    #pragma unroll
    for (int i = 0; i < 32; ++i) { ma += gelu_erf(sa[i] + ba); mb += gelu_erf(sb[i] + bbv); }
    ma *= (1.f / 32.f); mb *= (1.f / 32.f);

    int oa = co0 * NPOOL + pg, ob = co1 * NPOOL + pg;
    float ra = (ma - bnm[oa]) * rsqrtf(bnv[oa] + 1e-5f) * bng[oa] + bnb[oa];
    float rb = (mb - bnm[ob]) * rsqrtf(bnv[ob] + 1e-5f) * bng[ob] + bnb[ob];
    h[(size_t)b * HD + oa] = ra;
    h[(size_t)b * HD + ob] = rb;
}

// ---------------- Kernel B: fc1+GELU, fc2, gumbel softmax, top-2, expert row lists ----------
__global__ __launch_bounds__(256) void krouter_fc(
    const float* __restrict__ h, const float* __restrict__ f1w, const float* __restrict__ f1b,
    const float* __restrict__ f2w, const float* __restrict__ f2b,
    const float* __restrict__ gu,
    int* __restrict__ top2e, float* __restrict__ top2w,
    int* __restrict__ cnt, int* __restrict__ rowlist, float* __restrict__ roww)
{
    __shared__ float hs[8 * HD];
    __shared__ float h1s[8 * F1];
    __shared__ float lg[8 * NE];

    int bb = blockIdx.x * 8;
    int t = threadIdx.x;

    const f32x4* hg = (const f32x4*)(h + (size_t)bb * HD);
    f32x4* hs4 = (f32x4*)hs;
    #pragma unroll
    for (int u = 0; u < 8; ++u) hs4[t + 256 * u] = hg[t + 256 * u];
    __syncthreads();

    int j = t & 127;
    int pr = t >> 7;
    float acc[4] = {0.f, 0.f, 0.f, 0.f};
    const f32x4* w4 = (const f32x4*)(f1w + (size_t)j * HD);
    for (int k4 = 0; k4 < 256; ++k4) {
        f32x4 w = w4[k4];
        #pragma unroll
        for (int g = 0; g < 4; ++g) {
            f32x4 hv = hs4[(pr * 4 + g) * 256 + k4];
            acc[g] += w[0]*hv[0] + w[1]*hv[1] + w[2]*hv[2] + w[3]*hv[3];
        }
    }
    float bj = f1b[j];
    #pragma unroll
    for (int g = 0; g < 4; ++g) h1s[(pr * 4 + g) * F1 + j] = gelu_erf(acc[g] + bj);
    __syncthreads();

    if (t < 64) {
        int bi = t >> 3, e = t & 7;
        float s = f2b[e];
        const float* w = f2w + e * F1;
        const float* hh = h1s + bi * F1;
        #pragma unroll 8
        for (int k = 0; k < F1; ++k) s += hh[k] * w[k];
        lg[bi * NE + e] = s;
    }
    __syncthreads();

    if (t < 8) {
        int bi = t; int b = bb + bi;
        float r[NE];
        float mx = -1e30f;
        #pragma unroll
        for (int e = 0; e < NE; ++e) {
            float g = -logf(-logf(gu[b * NE + e]));
            r[e] = lg[bi * NE + e] + g;
            mx = fmaxf(mx, r[e]);
        }
        float sum = 0.f;
        #pragma unroll
        for (int e = 0; e < NE; ++e) { r[e] = expf(r[e] - mx); sum += r[e]; }
        float inv = 1.f / sum;
        #pragma unroll
        for (int e = 0; e < NE; ++e) r[e] *= inv;
        int e0 = 0; float v0 = r[0];
        #pragma unroll
        for (int e = 1; e < NE; ++e) if (r[e] > v0) { v0 = r[e]; e0 = e; }
        int e1 = -1; float v1 = -1.f;
        #pragma unroll
        for (int e = 0; e < NE; ++e) { if (e == e0) continue; if (r[e] > v1) { v1 = r[e]; e1 = e; } }
        float den = v0 + v1 + 1e-8f;
        float w0 = v0 / den, w1 = v1 / den;
        top2e[b * 2 + 0] = e0; top2e[b * 2 + 1] = e1;
        top2w[b * 2 + 0] = w0; top2w[b * 2 + 1] = w1;
        int p0 = atomicAdd(&cnt[e0], 1);
        rowlist[e0 * NB + p0] = b * 2 + 0; roww[e0 * NB + p0] = w0;
        int p1 = atomicAdd(&cnt[e1], 1);
        rowlist[e1 * NB + p1] = b * 2 + 1; roww[e1 * NB + p1] = w1;
    }
}

// ---------------- Kernel C: gathered expert GEMM — full-DMA counted-vmcnt pipeline -------
// MT=256, NT=128, BK=32; 512 thr (8 waves 4m x 2n, wave tile 64x64). LDS 128KB, 1 blk/CU.
// A: bf16 x gathered via per-lane-source global_load_lds (2 instr/wave/step).
// B: fp32 ew via global_load_lds (2 instr/wave/step), source chunk-XOR pre-swizzled.
// Both 2 steps ahead into 4 buffers. Steady wait = s_waitcnt vmcnt(8): drains exactly
// step-s's 4 DMAs; 8 stay in flight across the barrier. No ds_writes, no reg staging.
__global__ __launch_bounds__(512, 2) void kgemm(
    const unsigned short* __restrict__ xb, const float* __restrict__ ew,
    const int* __restrict__ cnt, const int* __restrict__ rowlist, const float* __restrict__ roww,
    unsigned short* __restrict__ ypart, int nkc, int kch)
{
    // bijective XCD-chunk swizzle: contiguous wg range per XCD (one expert per XCD @nkc=16)
    int nwg = gridDim.x;
    int cpx = nwg >> 3;
    int wg = (blockIdx.x & 7) * cpx + (blockIdx.x >> 3);
    int nt = wg % 6;
    int kc = (wg / 6) % nkc;
    int e  = wg / (6 * nkc);
    int cn = cnt[e];
    if (cn <= 0) return;

    __shared__ __align__(16) char As[NBUF][MT * 64];       // 4 x 16KB bf16 [m][4x16B swz]
    __shared__ __align__(16) char Bs[NBUF][BK * NT * 4];   // 4 x 16KB fp32 [k][32x16B swz]

    int t = threadIdx.x;
    int wid = t >> 6, lane = t & 63;
    int wm = wid >> 1, wn = wid & 1;
    int g = lane >> 4;
    int NS = kch / BK;
    int k0 = kc * kch;

    // --- B DMA constants: instr i covers rows wid*4+i*2+(lane>>5), chunk (lane&31)^keyb ---
    const char* gB = (const char*)ew + (size_t)e * DIN * DOUT * 4
                   + (size_t)k0 * (DOUT * 4) + nt * NT * 4;
    int keyb = wid >> 1;
    int brow0 = wid * 4 + (lane >> 5);
    const char* gpB0 = gB + (size_t)brow0 * (DOUT * 4) + ((size_t)((lane & 31) ^ keyb) << 4);
    const char* gpB1 = gpB0 + 2 * (DOUT * 4);
    int ldsB0 = wid * 2048, ldsB1 = wid * 2048 + 1024;

    // --- A DMA constants: instr i covers rows wid*32+i*16+(lane>>2), k-quarter swz ---
    int keya = ((lane >> 2) ^ (lane >> 4)) & 3;
    int aq = (lane & 3) ^ keya;                     // source k-quarter (8 bf16 = 16B)
    int ldsA0 = wid * 2048, ldsA1 = wid * 2048 + 1024;

    // --- MFMA LDS read offsets (constant across steps) ---
    int af_off[4];
    #pragma unroll
    for (int mi = 0; mi < 4; ++mi) {
        int m = wm * 64 + mi * 16 + (lane & 15);
        int key = ((m & 3) ^ ((m >> 2) & 3));
        af_off[mi] = m * 64 + ((g ^ key) << 4);
    }
    int cb[4];
    #pragma unroll
    for (int ni = 0; ni < 4; ++ni) {
        int n = wn * 64 + ni * 16 + (lane & 15);
        cb[ni] = (((n >> 2) ^ g) << 4) + ((n & 3) << 2);
    }

    for (int row0 = 0; row0 < cn; row0 += MT) {
        int mloc = min(MT, cn - row0);
        bool wact = (wm * 64 < mloc);

        // per-pass A gather source bases (2 rows per lane)
        int r0 = wid * 32 + (lane >> 2);
        int r1 = r0 + 16;
        size_t ab0 = (size_t)(rowlist[e * NB + row0 + min(r0, mloc - 1)] >> 1) * (DIN * 2);
        size_t ab1 = (size_t)(rowlist[e * NB + row0 + min(r1, mloc - 1)] >> 1) * (DIN * 2);
        const char* gpA0 = (const char*)xb + ab0 + (size_t)k0 * 2 + (aq << 4);
        const char* gpA1 = (const char*)xb + ab1 + (size_t)k0 * 2 + (aq << 4);

        f32x4 acc[4][4];
        #pragma unroll
        for (int i = 0; i < 4; ++i)
            #pragma unroll
            for (int jj = 0; jj < 4; ++jj) acc[i][jj] = (f32x4){0.f, 0.f, 0.f, 0.f};

        auto stage = [&](int s) {    // 4 DMA instr: B x2 then A x2, all -> buffers s&3
            int bi = s & (NBUF - 1);
            size_t bo = (size_t)s * (BK * DOUT * 4);
            gload_lds16(gpB0 + bo, (char*)Bs[bi] + ldsB0);
            gload_lds16(gpB1 + bo, (char*)Bs[bi] + ldsB1);
            size_t ao = (size_t)s * (BK * 2);
            gload_lds16(gpA0 + ao, (char*)As[bi] + ldsA0);
            gload_lds16(gpA1 + ao, (char*)As[bi] + ldsA1);
        };

        // prologue: steps 0,1 in flight
        stage(0);
        if (1 < NS) stage(1);

        for (int s = 0; s < NS; ++s) {
            if (s + 2 < NS) stage(s + 2);
            __builtin_amdgcn_sched_barrier(0);
            if (s + 2 < NS)      asm volatile("s_waitcnt vmcnt(8)" ::: "memory");
            else if (s + 1 < NS) asm volatile("s_waitcnt vmcnt(4)" ::: "memory");
            else                 asm volatile("s_waitcnt vmcnt(0)" ::: "memory");
            __builtin_amdgcn_sched_barrier(0);
            __builtin_amdgcn_s_barrier();
            __builtin_amdgcn_sched_barrier(0);

            if (wact) {
                const char* Ab = As[s & (NBUF - 1)];
                const char* Bb = Bs[s & (NBUF - 1)];
                __builtin_amdgcn_s_setprio(1);
                s16x8 af[4];
                #pragma unroll
                for (int mi = 0; mi < 4; ++mi)
                    af[mi] = *(const s16x8*)(Ab + af_off[mi]);
                #pragma unroll
                for (int ni = 0; ni < 4; ++ni) {
                    float v[8];
                    #pragma unroll
                    for (int j = 0; j < 8; ++j)
                        v[j] = *(const float*)(Bb + g * 4096 + j * 512 + cb[ni]);
                    union { u32x4 u; s16x8 v8; } bf;
                    bf.u[0] = cvt_pk(v[0], v[1]); bf.u[1] = cvt_pk(v[2], v[3]);
                    bf.u[2] = cvt_pk(v[4], v[5]); bf.u[3] = cvt_pk(v[6], v[7]);
                    #pragma unroll
                    for (int mi = 0; mi < 4; ++mi)
                        acc[mi][ni] = __builtin_amdgcn_mfma_f32_16x16x32_bf16(af[mi], bf.v8, acc[mi][ni], 0, 0, 0);
                }
                __builtin_amdgcn_s_setprio(0);
            }
        }

        // ---- epilogue: gate weight, bf16 scatter to per-(slot,kc) partial plane ----
        if (wact) {
            #pragma unroll
            for (int mi = 0; mi < 4; ++mi) {
                #pragma unroll
                for (int rg = 0; rg < 4; ++rg) {
                    int m = wm * 64 + mi * 16 + g * 4 + rg;
                    if (m < mloc) {
                        int ent = rowlist[e * NB + row0 + m];
                        float wgt = roww[e * NB + row0 + m];
                        int ob = ent >> 1, slot = ent & 1;
                        unsigned short* dst = ypart + ((size_t)(slot * nkc + kc) * NB + ob) * DOUT
                                            + nt * NT + wn * 64 + (lane & 15);
                        #pragma unroll
                        for (int ni = 0; ni < 4; ++ni)
                            dst[ni * 16] = f2bf_u(acc[mi][ni][rg] * wgt);
                    }
                }
            }
        }
        // full drain between (rare) multi-pass iterations
        asm volatile("s_waitcnt vmcnt(0) lgkmcnt(0)" ::: "memory");
        __builtin_amdgcn_s_barrier();
    }
}

// ---------------- Kernel D: combine bf16 partial planes + weighted expert bias ------------
__global__ __launch_bounds__(256) void kcombine(
    const unsigned short* __restrict__ ypart,
    const int* __restrict__ top2e, const float* __restrict__ top2w,
    const float* __restrict__ eb, float* __restrict__ out, int nplanes)
{
    int b = blockIdx.y;
    int n = blockIdx.x * 256 + threadIdx.x;
    float s = 0.f;
    for (int p = 0; p < nplanes; ++p) {
        unsigned v = ypart[((size_t)p * NB + b) * DOUT + n];
        union { unsigned u; float f; } c; c.u = v << 16;
        s += c.f;
    }
    int e0 = top2e[b * 2], e1 = top2e[b * 2 + 1];
    float w0 = top2w[b * 2], w1 = top2w[b * 2 + 1];
    s += w0 * eb[e0 * DOUT + n] + w1 * eb[e1 * DOUT + n];
    out[(size_t)b * DOUT + n] = s;
}

extern "C" void kernel_launch(void* const* d_in, const int* in_sizes, int n_in,
                              void* d_out, int out_size, void* d_ws, size_t ws_size,
                              hipStream_t stream)
{
    const float* x   = (const float*)d_in[0];
    const float* gu  = (const float*)d_in[1];
    const float* cw  = (const float*)d_in[2];
    const float* cb  = (const float*)d_in[3];
    const float* bng = (const float*)d_in[4];
    const float* bnb = (const float*)d_in[5];
    const float* bnm = (const float*)d_in[6];
    const float* bnv = (const float*)d_in[7];
    const float* f1w = (const float*)d_in[8];
    const float* f1b = (const float*)d_in[9];
    const float* f2w = (const float*)d_in[10];
    const float* f2b = (const float*)d_in[11];
    const float* ew  = (const float*)d_in[12];
    const float* eb  = (const float*)d_in[13];

    int nkc = (ws_size >= (size_t)48 * 1024 * 1024) ? 16 : 8;
    int kch = DIN / nkc;

    char* ws = (char*)d_ws;
    size_t off = 0;
    float* h       = (float*)(ws + off); off += (size_t)NB * HD * 4;
    int*   top2e   = (int*)(ws + off);   off += (size_t)NB * 2 * 4;
    float* top2w   = (float*)(ws + off); off += (size_t)NB * 2 * 4;
    int*   cnt     = (int*)(ws + off);   off += 256;
    int*   rowlist = (int*)(ws + off);   off += (size_t)NE * NB * 4;
    float* roww    = (float*)(ws + off); off += (size_t)NE * NB * 4;
    unsigned short* xbuf = (unsigned short*)(ws + off);
    off += (size_t)NB * DIN * 2;                               // 16 MB bf16 x
    unsigned short* ypart = (unsigned short*)(ws + off);
    off += (size_t)2 * nkc * NB * DOUT * 2;

    kcvt<<<NB * DIN / 8 / 256, 256, 0, stream>>>(x, xbuf);
    krouter_conv<<<dim3(2, NB), 256, 0, stream>>>(x, cw, cb, bng, bnb, bnm, bnv, h, cnt);
    krouter_fc<<<NB / 8, 256, 0, stream>>>(h, f1w, f1b, f2w, f2b, gu,
                                           top2e, top2w, cnt, rowlist, roww);
    kgemm<<<NE * nkc * 6, 512, 0, stream>>>(xbuf, ew, cnt, rowlist, roww, ypart, nkc, kch);
    kcombine<<<dim3(3, NB), 256, 0, stream>>>(ypart, top2e, top2w, eb, (float*)d_out, 2 * nkc);
}